// Round 11
// baseline (268.057 us; speedup 1.0000x reference)
//
#include <hip/hip_runtime.h>

namespace {

constexpr int LEN   = 160;
constexpr int PLANE = LEN * LEN;
constexpr int VOL   = LEN * PLANE;
constexpr float INV_SZ = 1.0f / 125.0f;
constexpr float EPS_   = 1e-10f;

constexpr int TX = 32, TY = 32, ZC = 4;   // ZC=4 -> 2000 blocks (7.8/CU)
constexpr int RY = 36, RW = 40;    // raw tile rows / padded width (cols 2..37 valid)
constexpr int XSW = 36;            // xs row stride
constexpr int NCHZ = LEN / ZC;     // 40
constexpr int BLK = 256;           // thread owns a 4-px x-quad

__device__ __forceinline__ int clampi(int v) {
  return v < 0 ? 0 : (v > LEN - 1 ? LEN - 1 : v);
}
__device__ __forceinline__ float4 ld4(const float* p) { return *(const float4*)p; }
__device__ __forceinline__ void st4(float* p, float4 v) { *(float4*)p = v; }
__device__ __forceinline__ float4 f4add(float4 a, float4 b) {
  return make_float4(a.x + b.x, a.y + b.y, a.z + b.z, a.w + b.w);
}
__device__ __forceinline__ float rcp_(float x) { return __builtin_amdgcn_rcpf(x); }

// x-sum for one row-quad: 3 aligned b128 reads -> 4 sliding 5-tap sums.
template <int SQ>
__device__ __forceinline__ float4 xquad(const float (*raw)[RW], int row, int q) {
  float4 a0 = ld4(&raw[row][4 * q]);
  float4 a1 = ld4(&raw[row][4 * q + 4]);
  float4 a2 = ld4(&raw[row][4 * q + 8]);
  float f2 = a0.z, f3 = a0.w, f4 = a1.x, f5 = a1.y, f6 = a1.z, f7 = a1.w,
        f8 = a2.x, f9 = a2.y;
  if (SQ) { f2 *= f2; f3 *= f3; f4 *= f4; f5 *= f5; f6 *= f6; f7 *= f7; f8 *= f8; f9 *= f9; }
  float s0 = f2 + f3 + f4 + f5 + f6;
  float s1 = s0 - f2 + f7;
  float s2 = s1 - f3 + f8;
  float s3 = s2 - f4 + f9;
  return make_float4(s0, s1, s2, s3);
}

// ---------------------------------------------------------------------------
// Two-field slab box3, quad-per-thread, runtime z-loop, explicit ring shifts.
// (R7 structure verbatim — known to run; only ZC changed 8->4 for occupancy.)
// MODE 0: outA = inA - box3(inA)/125 ; outB likewise.
// MODE 1: outA = (inA/(sqrt(box3(inA^2)/125)+eps))*(inB/(sqrt(box3(inB^2)/125)+eps))
// ---------------------------------------------------------------------------
template <int MODE>
__global__ __launch_bounds__(BLK, 2) void slab2(const float* __restrict__ inA,
                                                const float* __restrict__ inB,
                                                float* __restrict__ outA,
                                                float* __restrict__ outB) {
  __shared__ float rawA[RY][RW], rawB[RY][RW];
  __shared__ float xsA[RY][XSW], xsB[RY][XSW];

  const int tid = threadIdx.x;
  const int x0 = blockIdx.x * TX, y0 = blockIdx.y * TY;
  const int z0 = (blockIdx.z % NCHZ) * ZC;
  const size_t base = (size_t)(blockIdx.z / NCHZ) * VOL;

  const int row0 = tid >> 3, q0 = tid & 7;      // owned quad; core/xs task 0
  const int row1 = 32 + (tid >> 3);             // core/xs task 1 (tid<32)
  const int off0 = clampi(y0 - 2 + row0) * LEN + x0 + 4 * q0;
  const int off1 = (tid < 32) ? clampi(y0 - 2 + row1) * LEN + x0 + 4 * q0 : 0;

  // edge scalars: 144 per field (36 rows x cols {2,3,36,37})
  const bool hasEA = tid < 144;
  const bool hasEB = (tid >= 144) || (tid < 32);
  const int pa = hasEA ? tid : 0;
  const int erA = pa >> 2, ccA = pa & 3;
  const int elA = ccA < 2 ? 2 + ccA : 34 + ccA;
  const int eoffA = clampi(y0 - 2 + erA) * LEN + clampi(x0 + elA - 4);
  const int pb_ = hasEB ? (tid >= 144 ? tid - 144 : 112 + tid) : 0;
  const int erB = pb_ >> 2, ccB = pb_ & 3;
  const int elB = ccB < 2 ? 2 + ccB : 34 + ccB;
  const int eoffB = clampi(y0 - 2 + erB) * LEN + clampi(x0 + elB - 4);

  float4 pA0, pB0, pA1, pB1;
  float eA = 0.f, eB = 0.f;
  float4 rA0, rA1, rA2, rA3, rA4, rB0, rB1, rB2, rB3, rB4;   // ys z-ring
  float4 cA0, cA1, cA2, cB0, cB1, cB2;                       // center ring (lag 2)
  rA0 = rA1 = rA2 = rA3 = rA4 = make_float4(0.f, 0.f, 0.f, 0.f);
  rB0 = rB1 = rB2 = rB3 = rB4 = rA0;
  cA0 = cA1 = cA2 = cB0 = cB1 = cB2 = rA0;

  auto loadPlane = [&](int zp) {
    const size_t pbz = base + (size_t)clampi(zp) * PLANE;
    pA0 = ld4(inA + pbz + off0);
    pB0 = ld4(inB + pbz + off0);
    if (tid < 32) { pA1 = ld4(inA + pbz + off1); pB1 = ld4(inB + pbz + off1); }
    if (hasEA) eA = inA[pbz + eoffA];
    if (hasEB) eB = inB[pbz + eoffB];
  };
  auto deposit = [&]() {
    st4(&rawA[row0][4 + 4 * q0], pA0);
    st4(&rawB[row0][4 + 4 * q0], pB0);
    if (tid < 32) { st4(&rawA[row1][4 + 4 * q0], pA1); st4(&rawB[row1][4 + 4 * q0], pB1); }
    if (hasEA) rawA[erA][elA] = eA;
    if (hasEB) rawB[erB][elB] = eB;
  };

  loadPlane(z0 - 2);
  deposit();
  __syncthreads();

  for (int zp = z0 - 2; zp <= z0 + ZC + 1; ++zp) {
    if (zp <= z0 + ZC) loadPlane(zp + 1);   // prefetch next plane into registers

    // x-sums of plane zp (square on read for MODE 1)
    st4(&xsA[row0][4 * q0], xquad<MODE == 1>(rawA, row0, q0));
    st4(&xsB[row0][4 * q0], xquad<MODE == 1>(rawB, row0, q0));
    if (tid < 32) {
      st4(&xsA[row1][4 * q0], xquad<MODE == 1>(rawA, row1, q0));
      st4(&xsB[row1][4 * q0], xquad<MODE == 1>(rawB, row1, q0));
    }
    // center ring shift + stash (unsquared raw)
    cA0 = cA1; cA1 = cA2; cA2 = ld4(&rawA[row0 + 2][4 * q0 + 4]);
    cB0 = cB1; cB1 = cB2; cB2 = ld4(&rawB[row0 + 2][4 * q0 + 4]);

    __syncthreads();            // raw consumed; xs published

    if (zp <= z0 + ZC) deposit();  // raw <- plane zp+1

    // y-sums of plane zp
    float4 ysA = make_float4(0.f, 0.f, 0.f, 0.f), ysB = ysA;
#pragma unroll
    for (int k = 0; k < 5; ++k) {
      ysA = f4add(ysA, ld4(&xsA[row0 + k][4 * q0]));
      ysB = f4add(ysB, ld4(&xsB[row0 + k][4 * q0]));
    }
    // z-ring shift
    rA0 = rA1; rA1 = rA2; rA2 = rA3; rA3 = rA4; rA4 = ysA;
    rB0 = rB1; rB1 = rB2; rB2 = rB3; rB3 = rB4; rB4 = ysB;

    if (zp >= z0 + 2) {
      const int zo = zp - 2;
      float4 bsA = f4add(f4add(f4add(rA0, rA1), f4add(rA2, rA3)), rA4);
      float4 bsB = f4add(f4add(f4add(rB0, rB1), f4add(rB2, rB3)), rB4);
      size_t g = base + (size_t)zo * PLANE + (size_t)(y0 + row0) * LEN + (x0 + 4 * q0);
      if (MODE == 0) {
        st4(outA + g, make_float4(cA0.x - bsA.x * INV_SZ, cA0.y - bsA.y * INV_SZ,
                                  cA0.z - bsA.z * INV_SZ, cA0.w - bsA.w * INV_SZ));
        st4(outB + g, make_float4(cB0.x - bsB.x * INV_SZ, cB0.y - bsB.y * INV_SZ,
                                  cB0.z - bsB.z * INV_SZ, cB0.w - bsB.w * INV_SZ));
      } else {
        float4 o;
        o.x = (cA0.x * rcp_(sqrtf(bsA.x * INV_SZ) + EPS_)) * (cB0.x * rcp_(sqrtf(bsB.x * INV_SZ) + EPS_));
        o.y = (cA0.y * rcp_(sqrtf(bsA.y * INV_SZ) + EPS_)) * (cB0.y * rcp_(sqrtf(bsB.y * INV_SZ) + EPS_));
        o.z = (cA0.z * rcp_(sqrtf(bsA.z * INV_SZ) + EPS_)) * (cB0.z * rcp_(sqrtf(bsB.z * INV_SZ) + EPS_));
        o.w = (cA0.w * rcp_(sqrtf(bsA.w * INV_SZ) + EPS_)) * (cB0.w * rcp_(sqrtf(bsB.w * INV_SZ) + EPS_));
        st4(outA + g, o);
      }
    }
    __syncthreads();            // xs consumed; raw(zp+1) published
  }
}

// ---------------------------------------------------------------------------
// Stage C: cross = box3(p); acc += cross^2 * mask; block reduce -> atomicAdd.
// ---------------------------------------------------------------------------
__global__ __launch_bounds__(BLK, 2) void slab1_reduce(const float* __restrict__ p,
                                                       const float* __restrict__ mask,
                                                       float* __restrict__ out) {
  __shared__ float raw[RY][RW];
  __shared__ float xs[RY][XSW];
  __shared__ float wsum[BLK / 64];

  const int tid = threadIdx.x;
  const int x0 = blockIdx.x * TX, y0 = blockIdx.y * TY;
  const int z0 = (blockIdx.z % NCHZ) * ZC;
  const size_t base = (size_t)(blockIdx.z / NCHZ) * VOL;

  const int row0 = tid >> 3, q0 = tid & 7;
  const int row1 = 32 + (tid >> 3);
  const int off0 = clampi(y0 - 2 + row0) * LEN + x0 + 4 * q0;
  const int off1 = (tid < 32) ? clampi(y0 - 2 + row1) * LEN + x0 + 4 * q0 : 0;

  const bool hasE = tid < 144;
  const int pe = hasE ? tid : 0;
  const int er = pe >> 2, ce = pe & 3;
  const int el = ce < 2 ? 2 + ce : 34 + ce;
  const int eoff = clampi(y0 - 2 + er) * LEN + clampi(x0 + el - 4);

  float4 pc0, pc1;
  float ev = 0.f;
  float4 r0, r1, r2, r3, r4;
  r0 = r1 = r2 = r3 = r4 = make_float4(0.f, 0.f, 0.f, 0.f);
  float acc = 0.f;

  auto loadPlane = [&](int zp) {
    const size_t pbz = base + (size_t)clampi(zp) * PLANE;
    pc0 = ld4(p + pbz + off0);
    if (tid < 32) pc1 = ld4(p + pbz + off1);
    if (hasE) ev = p[pbz + eoff];
  };
  auto deposit = [&]() {
    st4(&raw[row0][4 + 4 * q0], pc0);
    if (tid < 32) st4(&raw[row1][4 + 4 * q0], pc1);
    if (hasE) raw[er][el] = ev;
  };

  loadPlane(z0 - 2);
  deposit();
  __syncthreads();

  for (int zp = z0 - 2; zp <= z0 + ZC + 1; ++zp) {
    if (zp <= z0 + ZC) loadPlane(zp + 1);

    st4(&xs[row0][4 * q0], xquad<0>(raw, row0, q0));
    if (tid < 32) st4(&xs[row1][4 * q0], xquad<0>(raw, row1, q0));

    __syncthreads();

    if (zp <= z0 + ZC) deposit();

    float4 ys = make_float4(0.f, 0.f, 0.f, 0.f);
#pragma unroll
    for (int k = 0; k < 5; ++k) ys = f4add(ys, ld4(&xs[row0 + k][4 * q0]));
    r0 = r1; r1 = r2; r2 = r3; r3 = r4; r4 = ys;

    if (zp >= z0 + 2) {
      const int zo = zp - 2;
      float4 bs = f4add(f4add(f4add(r0, r1), f4add(r2, r3)), r4);
      size_t g = base + (size_t)zo * PLANE + (size_t)(y0 + row0) * LEN + (x0 + 4 * q0);
      float4 mk = ld4(mask + g);
      acc += bs.x * bs.x * mk.x + bs.y * bs.y * mk.y +
             bs.z * bs.z * mk.z + bs.w * bs.w * mk.w;
    }
    __syncthreads();
  }

#pragma unroll
  for (int o = 32; o > 0; o >>= 1) acc += __shfl_down(acc, o, 64);
  int lane = tid & 63, wid = tid >> 6;
  if (lane == 0) wsum[wid] = acc;
  __syncthreads();
  if (tid == 0) {
    float t = 0.f;
#pragma unroll
    for (int w = 0; w < BLK / 64; ++w) t += wsum[w];
    atomicAdd(out, -t);
  }
}

}  // namespace

extern "C" void kernel_launch(void* const* d_in, const int* in_sizes, int n_in,
                              void* d_out, int out_size, void* d_ws, size_t ws_size,
                              hipStream_t stream) {
  const float* F    = (const float*)d_in[0];
  const float* M    = (const float*)d_in[1];
  const float* mask = (const float*)d_in[2];
  float* out = (float*)d_out;

  const size_t bufB = (size_t)(2 * VOL) * sizeof(float);
  char* ws = (char*)d_ws;
  float* dF = (float*)ws;
  float* dM = (float*)(ws + bufB);
  float* pB = (float*)(ws + 2 * bufB);

  hipMemsetAsync(d_out, 0, sizeof(float), stream);

  dim3 grd(LEN / TX, LEN / TY, NCHZ * 2), blk(BLK);

  slab2<0><<<grd, blk, 0, stream>>>(F, M, dF, dM);
  slab2<1><<<grd, blk, 0, stream>>>(dF, dM, pB, nullptr);
  slab1_reduce<<<grd, blk, 0, stream>>>(pB, mask, out);
}

// Round 12
// 241.574 us; speedup vs baseline: 1.1096x; 1.1096x over previous
//
#include <hip/hip_runtime.h>

namespace {

constexpr int LEN   = 160;
constexpr int PLANE = LEN * LEN;
constexpr int VOL   = LEN * PLANE;
constexpr float INV_SZ = 1.0f / 125.0f;
constexpr float EPS_   = 1e-10f;

constexpr int TX = 32, TY = 32, ZC = 8;
constexpr int RY = 36;             // halo rows
constexpr int RS = 36;             // LDS row stride (cols 0..31 used; 144 B keeps 16B align)
constexpr int NCHZ = LEN / ZC;     // 20
constexpr int BLK = 256;           // thread owns a 4-px x-quad

__device__ __forceinline__ int clampi(int v) {
  return v < 0 ? 0 : (v > LEN - 1 ? LEN - 1 : v);
}
__device__ __forceinline__ float4 ld4(const float* p) { return *(const float4*)p; }
__device__ __forceinline__ void st4(float* p, float4 v) { *(float4*)p = v; }
__device__ __forceinline__ float4 f4add(float4 a, float4 b) {
  return make_float4(a.x + b.x, a.y + b.y, a.z + b.z, a.w + b.w);
}
__device__ __forceinline__ float rcp_(float x) { return __builtin_amdgcn_rcpf(x); }

// x-sum quad computed IN REGISTERS from the just-loaded quad + lane-neighbor
// quads (shfl) + row-edge scalars (q==0 / q==7 threads hold them).
// eL0,eL1 = g(x0-2),g(x0-1) for this row; eR0,eR1 = g(x0+32),g(x0+33).
template <int SQ>
__device__ __forceinline__ float4 xs_from_regs(float4 v, float eL0, float eL1,
                                               float eR0, float eR1, int q) {
  float lz = __shfl_up(v.z, 1, 64);    // lane-1's z  = g(4q-2)
  float lw = __shfl_up(v.w, 1, 64);    // lane-1's w  = g(4q-1)
  float rx = __shfl_down(v.x, 1, 64);  // lane+1's x  = g(4q+4)
  float ry = __shfl_down(v.y, 1, 64);  // lane+1's y  = g(4q+5)
  float a = (q == 0) ? eL0 : lz;
  float b = (q == 0) ? eL1 : lw;
  float g7 = (q == 7) ? eR0 : rx;
  float h = (q == 7) ? eR1 : ry;
  float c = v.x, d = v.y, e = v.z, f = v.w;
  if (SQ) { a*=a; b*=b; c*=c; d*=d; e*=e; f*=f; g7*=g7; h*=h; }
  float s0 = a + b + c + d + e;
  float s1 = s0 - a + f;
  float s2 = s1 - b + g7;
  float s3 = s2 - c + h;
  return make_float4(s0, s1, s2, s3);
}

// ---------------------------------------------------------------------------
// Two-field slab box3 (R7 skeleton: 2 barriers/plane, single raw buffer).
// x-sums now computed in registers (shfl) at deposit time — no xquad LDS reads.
// MODE 0: outA = inA - box3(inA)/125 ; outB likewise.
// MODE 1: outA = (inA/(sqrt(box3(inA^2)/125)+eps))*(inB/(sqrt(box3(inB^2)/125)+eps))
// ---------------------------------------------------------------------------
template <int MODE>
__global__ __launch_bounds__(BLK, 2) void slab2(const float* __restrict__ inA,
                                                const float* __restrict__ inB,
                                                float* __restrict__ outA,
                                                float* __restrict__ outB) {
  __shared__ float rawA[RY][RS], rawB[RY][RS];   // core only, for centers
  __shared__ float xsA[RY][RS],  xsB[RY][RS];

  const int tid = threadIdx.x;
  const int x0 = blockIdx.x * TX, y0 = blockIdx.y * TY;
  const int z0 = (blockIdx.z % NCHZ) * ZC;
  const size_t base = (size_t)(blockIdx.z / NCHZ) * VOL;

  const int row0 = tid >> 3, q0 = tid & 7;      // owned quad; task 0 row
  const int row1 = 32 + (tid >> 3);             // task 1 row (tid<32)
  const int rb0 = clampi(y0 - 2 + row0) * LEN;
  const int rb1 = (tid < 32) ? clampi(y0 - 2 + row1) * LEN : 0;
  const int off0 = rb0 + x0 + 4 * q0;
  const int off1 = rb1 + x0 + 4 * q0;
  const int xL0 = clampi(x0 - 2),  xL1 = clampi(x0 - 1);
  const int xR0 = clampi(x0 + 32), xR1 = clampi(x0 + 33);

  float4 pA0, pB0, pA1, pB1;
  float eA0[4] = {0,0,0,0}, eB0[4] = {0,0,0,0};   // [0,1]=left (q==0), [2,3]=right (q==7)
  float eA1[4] = {0,0,0,0}, eB1[4] = {0,0,0,0};
  float4 rA0, rA1, rA2, rA3, rA4, rB0, rB1, rB2, rB3, rB4;   // ys z-ring
  float4 cA0, cA1, cA2, cB0, cB1, cB2;                       // center ring (lag 2)
  rA0 = rA1 = rA2 = rA3 = rA4 = make_float4(0.f, 0.f, 0.f, 0.f);
  rB0 = rB1 = rB2 = rB3 = rB4 = rA0;
  cA0 = cA1 = cA2 = cB0 = cB1 = cB2 = rA0;

  auto loadPlane = [&](int zp) {
    const size_t pbz = base + (size_t)clampi(zp) * PLANE;
    pA0 = ld4(inA + pbz + off0);
    pB0 = ld4(inB + pbz + off0);
    if (q0 == 0) { eA0[0] = inA[pbz + rb0 + xL0]; eA0[1] = inA[pbz + rb0 + xL1];
                   eB0[0] = inB[pbz + rb0 + xL0]; eB0[1] = inB[pbz + rb0 + xL1]; }
    if (q0 == 7) { eA0[2] = inA[pbz + rb0 + xR0]; eA0[3] = inA[pbz + rb0 + xR1];
                   eB0[2] = inB[pbz + rb0 + xR0]; eB0[3] = inB[pbz + rb0 + xR1]; }
    if (tid < 32) {
      pA1 = ld4(inA + pbz + off1);
      pB1 = ld4(inB + pbz + off1);
      if (q0 == 0) { eA1[0] = inA[pbz + rb1 + xL0]; eA1[1] = inA[pbz + rb1 + xL1];
                     eB1[0] = inB[pbz + rb1 + xL0]; eB1[1] = inB[pbz + rb1 + xL1]; }
      if (q0 == 7) { eA1[2] = inA[pbz + rb1 + xR0]; eA1[3] = inA[pbz + rb1 + xR1];
                     eB1[2] = inB[pbz + rb1 + xR0]; eB1[3] = inB[pbz + rb1 + xR1]; }
    }
  };

  auto depositAll = [&]() {
    float4 xa = xs_from_regs<MODE == 1>(pA0, eA0[0], eA0[1], eA0[2], eA0[3], q0);
    float4 xb = xs_from_regs<MODE == 1>(pB0, eB0[0], eB0[1], eB0[2], eB0[3], q0);
    st4(&rawA[row0][4 * q0], pA0);
    st4(&rawB[row0][4 * q0], pB0);
    st4(&xsA[row0][4 * q0], xa);
    st4(&xsB[row0][4 * q0], xb);
    if (tid < 32) {
      float4 ya = xs_from_regs<MODE == 1>(pA1, eA1[0], eA1[1], eA1[2], eA1[3], q0);
      float4 yb = xs_from_regs<MODE == 1>(pB1, eB1[0], eB1[1], eB1[2], eB1[3], q0);
      st4(&rawA[row1][4 * q0], pA1);
      st4(&rawB[row1][4 * q0], pB1);
      st4(&xsA[row1][4 * q0], ya);
      st4(&xsB[row1][4 * q0], yb);
    }
  };

  loadPlane(z0 - 2);
  depositAll();
  __syncthreads();

  for (int zp = z0 - 2; zp <= z0 + ZC + 1; ++zp) {
    if (zp <= z0 + ZC) loadPlane(zp + 1);   // prefetch next plane into registers

    // READ phase on plane zp
    cA0 = cA1; cA1 = cA2; cA2 = ld4(&rawA[row0 + 2][4 * q0]);
    cB0 = cB1; cB1 = cB2; cB2 = ld4(&rawB[row0 + 2][4 * q0]);

    float4 ysA = make_float4(0.f, 0.f, 0.f, 0.f), ysB = ysA;
#pragma unroll
    for (int k = 0; k < 5; ++k) {
      ysA = f4add(ysA, ld4(&xsA[row0 + k][4 * q0]));
      ysB = f4add(ysB, ld4(&xsB[row0 + k][4 * q0]));
    }
    rA0 = rA1; rA1 = rA2; rA2 = rA3; rA3 = rA4; rA4 = ysA;
    rB0 = rB1; rB1 = rB2; rB2 = rB3; rB3 = rB4; rB4 = ysB;

    if (zp >= z0 + 2) {
      const int zo = zp - 2;
      float4 bsA = f4add(f4add(f4add(rA0, rA1), f4add(rA2, rA3)), rA4);
      float4 bsB = f4add(f4add(f4add(rB0, rB1), f4add(rB2, rB3)), rB4);
      size_t g = base + (size_t)zo * PLANE + (size_t)(y0 + row0) * LEN + (x0 + 4 * q0);
      if (MODE == 0) {
        st4(outA + g, make_float4(cA0.x - bsA.x * INV_SZ, cA0.y - bsA.y * INV_SZ,
                                  cA0.z - bsA.z * INV_SZ, cA0.w - bsA.w * INV_SZ));
        st4(outB + g, make_float4(cB0.x - bsB.x * INV_SZ, cB0.y - bsB.y * INV_SZ,
                                  cB0.z - bsB.z * INV_SZ, cB0.w - bsB.w * INV_SZ));
      } else {
        float4 o;
        o.x = (cA0.x * rcp_(sqrtf(bsA.x * INV_SZ) + EPS_)) * (cB0.x * rcp_(sqrtf(bsB.x * INV_SZ) + EPS_));
        o.y = (cA0.y * rcp_(sqrtf(bsA.y * INV_SZ) + EPS_)) * (cB0.y * rcp_(sqrtf(bsB.y * INV_SZ) + EPS_));
        o.z = (cA0.z * rcp_(sqrtf(bsA.z * INV_SZ) + EPS_)) * (cB0.z * rcp_(sqrtf(bsB.z * INV_SZ) + EPS_));
        o.w = (cA0.w * rcp_(sqrtf(bsA.w * INV_SZ) + EPS_)) * (cB0.w * rcp_(sqrtf(bsB.w * INV_SZ) + EPS_));
        st4(outA + g, o);
      }
    }
    __syncthreads();                        // reads of plane zp done

    if (zp <= z0 + ZC) depositAll();        // write plane zp+1 (raw + xs)
    __syncthreads();                        // writes visible
  }
}

// ---------------------------------------------------------------------------
// Stage C: cross = box3(p); acc += cross^2 * mask. xs-only LDS (no raw/centers).
// ---------------------------------------------------------------------------
__global__ __launch_bounds__(BLK, 2) void slab1_reduce(const float* __restrict__ p,
                                                       const float* __restrict__ mask,
                                                       float* __restrict__ out) {
  __shared__ float xs[RY][RS];
  __shared__ float wsum[BLK / 64];

  const int tid = threadIdx.x;
  const int x0 = blockIdx.x * TX, y0 = blockIdx.y * TY;
  const int z0 = (blockIdx.z % NCHZ) * ZC;
  const size_t base = (size_t)(blockIdx.z / NCHZ) * VOL;

  const int row0 = tid >> 3, q0 = tid & 7;
  const int row1 = 32 + (tid >> 3);
  const int rb0 = clampi(y0 - 2 + row0) * LEN;
  const int rb1 = (tid < 32) ? clampi(y0 - 2 + row1) * LEN : 0;
  const int off0 = rb0 + x0 + 4 * q0;
  const int off1 = rb1 + x0 + 4 * q0;
  const int xL0 = clampi(x0 - 2),  xL1 = clampi(x0 - 1);
  const int xR0 = clampi(x0 + 32), xR1 = clampi(x0 + 33);

  float4 pc0, pc1;
  float e0[4] = {0,0,0,0}, e1[4] = {0,0,0,0};
  float4 r0, r1, r2, r3, r4;
  r0 = r1 = r2 = r3 = r4 = make_float4(0.f, 0.f, 0.f, 0.f);
  float acc = 0.f;

  auto loadPlane = [&](int zp) {
    const size_t pbz = base + (size_t)clampi(zp) * PLANE;
    pc0 = ld4(p + pbz + off0);
    if (q0 == 0) { e0[0] = p[pbz + rb0 + xL0]; e0[1] = p[pbz + rb0 + xL1]; }
    if (q0 == 7) { e0[2] = p[pbz + rb0 + xR0]; e0[3] = p[pbz + rb0 + xR1]; }
    if (tid < 32) {
      pc1 = ld4(p + pbz + off1);
      if (q0 == 0) { e1[0] = p[pbz + rb1 + xL0]; e1[1] = p[pbz + rb1 + xL1]; }
      if (q0 == 7) { e1[2] = p[pbz + rb1 + xR0]; e1[3] = p[pbz + rb1 + xR1]; }
    }
  };
  auto depositAll = [&]() {
    float4 xa = xs_from_regs<0>(pc0, e0[0], e0[1], e0[2], e0[3], q0);
    st4(&xs[row0][4 * q0], xa);
    if (tid < 32) {
      float4 ya = xs_from_regs<0>(pc1, e1[0], e1[1], e1[2], e1[3], q0);
      st4(&xs[row1][4 * q0], ya);
    }
  };

  loadPlane(z0 - 2);
  depositAll();
  __syncthreads();

  for (int zp = z0 - 2; zp <= z0 + ZC + 1; ++zp) {
    if (zp <= z0 + ZC) loadPlane(zp + 1);

    float4 ys = make_float4(0.f, 0.f, 0.f, 0.f);
#pragma unroll
    for (int k = 0; k < 5; ++k) ys = f4add(ys, ld4(&xs[row0 + k][4 * q0]));
    r0 = r1; r1 = r2; r2 = r3; r3 = r4; r4 = ys;

    if (zp >= z0 + 2) {
      const int zo = zp - 2;
      float4 bs = f4add(f4add(f4add(r0, r1), f4add(r2, r3)), r4);
      size_t g = base + (size_t)zo * PLANE + (size_t)(y0 + row0) * LEN + (x0 + 4 * q0);
      float4 mk = ld4(mask + g);
      acc += bs.x * bs.x * mk.x + bs.y * bs.y * mk.y +
             bs.z * bs.z * mk.z + bs.w * bs.w * mk.w;
    }
    __syncthreads();

    if (zp <= z0 + ZC) depositAll();
    __syncthreads();
  }

#pragma unroll
  for (int o = 32; o > 0; o >>= 1) acc += __shfl_down(acc, o, 64);
  int lane = tid & 63, wid = tid >> 6;
  if (lane == 0) wsum[wid] = acc;
  __syncthreads();
  if (tid == 0) {
    float t = 0.f;
#pragma unroll
    for (int w = 0; w < BLK / 64; ++w) t += wsum[w];
    atomicAdd(out, -t);
  }
}

}  // namespace

extern "C" void kernel_launch(void* const* d_in, const int* in_sizes, int n_in,
                              void* d_out, int out_size, void* d_ws, size_t ws_size,
                              hipStream_t stream) {
  const float* F    = (const float*)d_in[0];
  const float* M    = (const float*)d_in[1];
  const float* mask = (const float*)d_in[2];
  float* out = (float*)d_out;

  const size_t bufB = (size_t)(2 * VOL) * sizeof(float);
  char* ws = (char*)d_ws;
  float* dF = (float*)ws;
  float* dM = (float*)(ws + bufB);
  float* pB = (float*)(ws + 2 * bufB);

  hipMemsetAsync(d_out, 0, sizeof(float), stream);

  dim3 grd(LEN / TX, LEN / TY, NCHZ * 2), blk(BLK);

  slab2<0><<<grd, blk, 0, stream>>>(F, M, dF, dM);
  slab2<1><<<grd, blk, 0, stream>>>(dF, dM, pB, nullptr);
  slab1_reduce<<<grd, blk, 0, stream>>>(pB, mask, out);
}

// Round 13
// 213.745 us; speedup vs baseline: 1.2541x; 1.1302x over previous
//
#include <hip/hip_runtime.h>

namespace {

constexpr int LEN   = 160;
constexpr int PLANE = LEN * LEN;
constexpr int VOL   = LEN * PLANE;
constexpr float INV_SZ = 1.0f / 125.0f;
constexpr float EPS_   = 1e-10f;

constexpr int TX = 32, TY = 32, ZC = 16;  // ZC=16: fewer halo planes
constexpr int RY = 36, RW = 40;    // raw rows / padded width (cols 2..37 valid)
constexpr int NCHZ = LEN / ZC;     // 10 -> 500 blocks
constexpr int BLK = 256;           // thread owns a 4-px x-quad
constexpr int ZIT2 = (ZC + 4) / 2; // 10 rounds, TWO planes per round

__device__ __forceinline__ int clampi(int v) {
  return v < 0 ? 0 : (v > LEN - 1 ? LEN - 1 : v);
}
__device__ __forceinline__ float4 ld4(const float* p) { return *(const float4*)p; }
__device__ __forceinline__ void st4(float* p, float4 v) { *(float4*)p = v; }
__device__ __forceinline__ float4 f4add(float4 a, float4 b) {
  return make_float4(a.x + b.x, a.y + b.y, a.z + b.z, a.w + b.w);
}
__device__ __forceinline__ float rcp_(float x) { return __builtin_amdgcn_rcpf(x); }

// x-sum for one row-quad: 3 aligned b128 reads -> 4 sliding 5-tap sums.
template <int SQ>
__device__ __forceinline__ float4 xquad(const float (*raw)[RW], int row, int q) {
  float4 a0 = ld4(&raw[row][4 * q]);
  float4 a1 = ld4(&raw[row][4 * q + 4]);
  float4 a2 = ld4(&raw[row][4 * q + 8]);
  float f2 = a0.z, f3 = a0.w, f4 = a1.x, f5 = a1.y, f6 = a1.z, f7 = a1.w,
        f8 = a2.x, f9 = a2.y;
  if (SQ) { f2 *= f2; f3 *= f3; f4 *= f4; f5 *= f5; f6 *= f6; f7 *= f7; f8 *= f8; f9 *= f9; }
  float s0 = f2 + f3 + f4 + f5 + f6;
  float s1 = s0 - f2 + f7;
  float s2 = s1 - f3 + f8;
  float s3 = s2 - f4 + f9;
  return make_float4(s0, s1, s2, s3);
}

// ---------------------------------------------------------------------------
// Two-field slab box3, TWO planes per barrier-round (1 barrier/plane).
// R7 skeleton otherwise. MODE 0: out = in - box3(in)/125 (both fields).
// MODE 1: outA = (inA/(sqrt(box3(inA^2)/125)+eps))*(inB/(sqrt(box3(inB^2)/125)+eps))
// ---------------------------------------------------------------------------
template <int MODE>
__global__ __launch_bounds__(BLK, 2) void slab2(const float* __restrict__ inA,
                                                const float* __restrict__ inB,
                                                float* __restrict__ outA,
                                                float* __restrict__ outB) {
  __shared__ float rawA[2][RY][RW], rawB[2][RY][RW];  // 23 KB
  __shared__ float xsA[2][RY][RW],  xsB[2][RY][RW];   // 23 KB

  const int tid = threadIdx.x;
  const int x0 = blockIdx.x * TX, y0 = blockIdx.y * TY;
  const int z0 = (blockIdx.z % NCHZ) * ZC;
  const size_t base = (size_t)(blockIdx.z / NCHZ) * VOL;

  const int row0 = tid >> 3, q0 = tid & 7;
  const int row1 = 32 + (tid >> 3);
  const int off0 = clampi(y0 - 2 + row0) * LEN + x0 + 4 * q0;
  const int off1 = (tid < 32) ? clampi(y0 - 2 + row1) * LEN + x0 + 4 * q0 : 0;

  // edge scalars: 144 per field (36 rows x cols {2,3,36,37})
  const bool hasEA = tid < 144;
  const bool hasEB = (tid >= 144) || (tid < 32);
  const int pa = hasEA ? tid : 0;
  const int erA = pa >> 2, ccA = pa & 3;
  const int elA = ccA < 2 ? 2 + ccA : 34 + ccA;
  const int eoffA = clampi(y0 - 2 + erA) * LEN + clampi(x0 + elA - 4);
  const int pb_ = hasEB ? (tid >= 144 ? tid - 144 : 112 + tid) : 0;
  const int erB = pb_ >> 2, ccB = pb_ & 3;
  const int elB = ccB < 2 ? 2 + ccB : 34 + ccB;
  const int eoffB = clampi(y0 - 2 + erB) * LEN + clampi(x0 + elB - 4);

  // two in-flight load sets (plane pair)
  float4 pA0s0, pB0s0, pA1s0, pB1s0;  float eAs0 = 0.f, eBs0 = 0.f;
  float4 pA0s1, pB0s1, pA1s1, pB1s1;  float eAs1 = 0.f, eBs1 = 0.f;

  float4 rA0, rA1, rA2, rA3, rA4, rB0, rB1, rB2, rB3, rB4;   // ys z-ring
  float4 cA0, cA1, cA2, cA3, cB0, cB1, cB2, cB3;             // center ring (depth 4)
  rA0 = rA1 = rA2 = rA3 = rA4 = make_float4(0.f, 0.f, 0.f, 0.f);
  rB0 = rB1 = rB2 = rB3 = rB4 = rA0;
  cA0 = cA1 = cA2 = cA3 = cB0 = cB1 = cB2 = cB3 = rA0;

  auto loadS0 = [&](int zp) {
    const size_t pbz = base + (size_t)clampi(zp) * PLANE;
    pA0s0 = ld4(inA + pbz + off0);
    pB0s0 = ld4(inB + pbz + off0);
    if (tid < 32) { pA1s0 = ld4(inA + pbz + off1); pB1s0 = ld4(inB + pbz + off1); }
    if (hasEA) eAs0 = inA[pbz + eoffA];
    if (hasEB) eBs0 = inB[pbz + eoffB];
  };
  auto loadS1 = [&](int zp) {
    const size_t pbz = base + (size_t)clampi(zp) * PLANE;
    pA0s1 = ld4(inA + pbz + off0);
    pB0s1 = ld4(inB + pbz + off0);
    if (tid < 32) { pA1s1 = ld4(inA + pbz + off1); pB1s1 = ld4(inB + pbz + off1); }
    if (hasEA) eAs1 = inA[pbz + eoffA];
    if (hasEB) eBs1 = inB[pbz + eoffB];
  };
  auto depS0 = [&]() {
    st4(&rawA[0][row0][4 + 4 * q0], pA0s0);
    st4(&rawB[0][row0][4 + 4 * q0], pB0s0);
    if (tid < 32) { st4(&rawA[0][row1][4 + 4 * q0], pA1s0);
                    st4(&rawB[0][row1][4 + 4 * q0], pB1s0); }
    if (hasEA) rawA[0][erA][elA] = eAs0;
    if (hasEB) rawB[0][erB][elB] = eBs0;
  };
  auto depS1 = [&]() {
    st4(&rawA[1][row0][4 + 4 * q0], pA0s1);
    st4(&rawB[1][row0][4 + 4 * q0], pB0s1);
    if (tid < 32) { st4(&rawA[1][row1][4 + 4 * q0], pA1s1);
                    st4(&rawB[1][row1][4 + 4 * q0], pB1s1); }
    if (hasEA) rawA[1][erA][elA] = eAs1;
    if (hasEB) rawB[1][erB][elB] = eBs1;
  };

  loadS0(z0 - 2); loadS1(z0 - 1);
  depS0(); depS1();
  __syncthreads();

#pragma unroll 1
  for (int r = 0; r < ZIT2; ++r) {
    const int zp0 = z0 - 2 + 2 * r;
    const bool more = (r < ZIT2 - 1);
    if (more) { loadS0(zp0 + 2); loadS1(zp0 + 3); }

    // ---- xs phase: both planes ----
    st4(&xsA[0][row0][4 * q0], xquad<MODE == 1>(rawA[0], row0, q0));
    st4(&xsB[0][row0][4 * q0], xquad<MODE == 1>(rawB[0], row0, q0));
    st4(&xsA[1][row0][4 * q0], xquad<MODE == 1>(rawA[1], row0, q0));
    st4(&xsB[1][row0][4 * q0], xquad<MODE == 1>(rawB[1], row0, q0));
    if (tid < 32) {
      st4(&xsA[0][row1][4 * q0], xquad<MODE == 1>(rawA[0], row1, q0));
      st4(&xsB[0][row1][4 * q0], xquad<MODE == 1>(rawB[0], row1, q0));
      st4(&xsA[1][row1][4 * q0], xquad<MODE == 1>(rawA[1], row1, q0));
      st4(&xsB[1][row1][4 * q0], xquad<MODE == 1>(rawB[1], row1, q0));
    }
    // center ring: two pushes (planes zp0, zp0+1)
    cA0 = cA1; cA1 = cA2; cA2 = cA3; cA3 = ld4(&rawA[0][row0 + 2][4 * q0 + 4]);
    cB0 = cB1; cB1 = cB2; cB2 = cB3; cB3 = ld4(&rawB[0][row0 + 2][4 * q0 + 4]);
    cA0 = cA1; cA1 = cA2; cA2 = cA3; cA3 = ld4(&rawA[1][row0 + 2][4 * q0 + 4]);
    cB0 = cB1; cB1 = cB2; cB2 = cB3; cB3 = ld4(&rawB[1][row0 + 2][4 * q0 + 4]);

    __syncthreads();            // raw consumed; xs published

    if (more) { depS0(); depS1(); }   // raw <- next pair

    // ---- plane zp0: ys, ring, output zo=zp0-2 ----
    {
      float4 ysA = make_float4(0.f, 0.f, 0.f, 0.f), ysB = ysA;
#pragma unroll
      for (int k = 0; k < 5; ++k) {
        ysA = f4add(ysA, ld4(&xsA[0][row0 + k][4 * q0]));
        ysB = f4add(ysB, ld4(&xsB[0][row0 + k][4 * q0]));
      }
      rA0 = rA1; rA1 = rA2; rA2 = rA3; rA3 = rA4; rA4 = ysA;
      rB0 = rB1; rB1 = rB2; rB2 = rB3; rB3 = rB4; rB4 = ysB;
      if (r >= 2) {
        float4 bsA = f4add(f4add(f4add(rA0, rA1), f4add(rA2, rA3)), rA4);
        float4 bsB = f4add(f4add(f4add(rB0, rB1), f4add(rB2, rB3)), rB4);
        size_t g = base + (size_t)(zp0 - 2) * PLANE +
                   (size_t)(y0 + row0) * LEN + (x0 + 4 * q0);
        if (MODE == 0) {
          st4(outA + g, make_float4(cA0.x - bsA.x * INV_SZ, cA0.y - bsA.y * INV_SZ,
                                    cA0.z - bsA.z * INV_SZ, cA0.w - bsA.w * INV_SZ));
          st4(outB + g, make_float4(cB0.x - bsB.x * INV_SZ, cB0.y - bsB.y * INV_SZ,
                                    cB0.z - bsB.z * INV_SZ, cB0.w - bsB.w * INV_SZ));
        } else {
          float4 o;
          o.x = (cA0.x * rcp_(sqrtf(bsA.x * INV_SZ) + EPS_)) * (cB0.x * rcp_(sqrtf(bsB.x * INV_SZ) + EPS_));
          o.y = (cA0.y * rcp_(sqrtf(bsA.y * INV_SZ) + EPS_)) * (cB0.y * rcp_(sqrtf(bsB.y * INV_SZ) + EPS_));
          o.z = (cA0.z * rcp_(sqrtf(bsA.z * INV_SZ) + EPS_)) * (cB0.z * rcp_(sqrtf(bsB.z * INV_SZ) + EPS_));
          o.w = (cA0.w * rcp_(sqrtf(bsA.w * INV_SZ) + EPS_)) * (cB0.w * rcp_(sqrtf(bsB.w * INV_SZ) + EPS_));
          st4(outA + g, o);
        }
      }
    }
    // ---- plane zp0+1: ys, ring, output zo=zp0-1 ----
    {
      float4 ysA = make_float4(0.f, 0.f, 0.f, 0.f), ysB = ysA;
#pragma unroll
      for (int k = 0; k < 5; ++k) {
        ysA = f4add(ysA, ld4(&xsA[1][row0 + k][4 * q0]));
        ysB = f4add(ysB, ld4(&xsB[1][row0 + k][4 * q0]));
      }
      rA0 = rA1; rA1 = rA2; rA2 = rA3; rA3 = rA4; rA4 = ysA;
      rB0 = rB1; rB1 = rB2; rB2 = rB3; rB3 = rB4; rB4 = ysB;
      if (r >= 2) {
        float4 bsA = f4add(f4add(f4add(rA0, rA1), f4add(rA2, rA3)), rA4);
        float4 bsB = f4add(f4add(f4add(rB0, rB1), f4add(rB2, rB3)), rB4);
        size_t g = base + (size_t)(zp0 - 1) * PLANE +
                   (size_t)(y0 + row0) * LEN + (x0 + 4 * q0);
        if (MODE == 0) {
          st4(outA + g, make_float4(cA1.x - bsA.x * INV_SZ, cA1.y - bsA.y * INV_SZ,
                                    cA1.z - bsA.z * INV_SZ, cA1.w - bsA.w * INV_SZ));
          st4(outB + g, make_float4(cB1.x - bsB.x * INV_SZ, cB1.y - bsB.y * INV_SZ,
                                    cB1.z - bsB.z * INV_SZ, cB1.w - bsB.w * INV_SZ));
        } else {
          float4 o;
          o.x = (cA1.x * rcp_(sqrtf(bsA.x * INV_SZ) + EPS_)) * (cB1.x * rcp_(sqrtf(bsB.x * INV_SZ) + EPS_));
          o.y = (cA1.y * rcp_(sqrtf(bsA.y * INV_SZ) + EPS_)) * (cB1.y * rcp_(sqrtf(bsB.y * INV_SZ) + EPS_));
          o.z = (cA1.z * rcp_(sqrtf(bsA.z * INV_SZ) + EPS_)) * (cB1.z * rcp_(sqrtf(bsB.z * INV_SZ) + EPS_));
          o.w = (cA1.w * rcp_(sqrtf(bsA.w * INV_SZ) + EPS_)) * (cB1.w * rcp_(sqrtf(bsB.w * INV_SZ) + EPS_));
          st4(outA + g, o);
        }
      }
    }
    __syncthreads();            // xs consumed; raw(next pair) published
  }
}

// ---------------------------------------------------------------------------
// Stage C: cross = box3(p); acc += cross^2*mask; two planes/round; reduce.
// ---------------------------------------------------------------------------
__global__ __launch_bounds__(BLK, 2) void slab1_reduce(const float* __restrict__ p,
                                                       const float* __restrict__ mask,
                                                       float* __restrict__ out) {
  __shared__ float raw[2][RY][RW];
  __shared__ float xs[2][RY][RW];
  __shared__ float wsum[BLK / 64];

  const int tid = threadIdx.x;
  const int x0 = blockIdx.x * TX, y0 = blockIdx.y * TY;
  const int z0 = (blockIdx.z % NCHZ) * ZC;
  const size_t base = (size_t)(blockIdx.z / NCHZ) * VOL;

  const int row0 = tid >> 3, q0 = tid & 7;
  const int row1 = 32 + (tid >> 3);
  const int off0 = clampi(y0 - 2 + row0) * LEN + x0 + 4 * q0;
  const int off1 = (tid < 32) ? clampi(y0 - 2 + row1) * LEN + x0 + 4 * q0 : 0;

  const bool hasE = tid < 144;
  const int pe = hasE ? tid : 0;
  const int er = pe >> 2, ce = pe & 3;
  const int el = ce < 2 ? 2 + ce : 34 + ce;
  const int eoff = clampi(y0 - 2 + er) * LEN + clampi(x0 + el - 4);

  float4 pc0s0, pc1s0;  float evs0 = 0.f;
  float4 pc0s1, pc1s1;  float evs1 = 0.f;
  float4 r0, r1, r2, r3, r4;
  r0 = r1 = r2 = r3 = r4 = make_float4(0.f, 0.f, 0.f, 0.f);
  float acc = 0.f;

  auto loadS0 = [&](int zp) {
    const size_t pbz = base + (size_t)clampi(zp) * PLANE;
    pc0s0 = ld4(p + pbz + off0);
    if (tid < 32) pc1s0 = ld4(p + pbz + off1);
    if (hasE) evs0 = p[pbz + eoff];
  };
  auto loadS1 = [&](int zp) {
    const size_t pbz = base + (size_t)clampi(zp) * PLANE;
    pc0s1 = ld4(p + pbz + off0);
    if (tid < 32) pc1s1 = ld4(p + pbz + off1);
    if (hasE) evs1 = p[pbz + eoff];
  };
  auto depS0 = [&]() {
    st4(&raw[0][row0][4 + 4 * q0], pc0s0);
    if (tid < 32) st4(&raw[0][row1][4 + 4 * q0], pc1s0);
    if (hasE) raw[0][er][el] = evs0;
  };
  auto depS1 = [&]() {
    st4(&raw[1][row0][4 + 4 * q0], pc0s1);
    if (tid < 32) st4(&raw[1][row1][4 + 4 * q0], pc1s1);
    if (hasE) raw[1][er][el] = evs1;
  };

  loadS0(z0 - 2); loadS1(z0 - 1);
  depS0(); depS1();
  __syncthreads();

#pragma unroll 1
  for (int r = 0; r < ZIT2; ++r) {
    const int zp0 = z0 - 2 + 2 * r;
    const bool more = (r < ZIT2 - 1);
    if (more) { loadS0(zp0 + 2); loadS1(zp0 + 3); }

    st4(&xs[0][row0][4 * q0], xquad<0>(raw[0], row0, q0));
    st4(&xs[1][row0][4 * q0], xquad<0>(raw[1], row0, q0));
    if (tid < 32) {
      st4(&xs[0][row1][4 * q0], xquad<0>(raw[0], row1, q0));
      st4(&xs[1][row1][4 * q0], xquad<0>(raw[1], row1, q0));
    }
    __syncthreads();

    if (more) { depS0(); depS1(); }

    {
      float4 ys = make_float4(0.f, 0.f, 0.f, 0.f);
#pragma unroll
      for (int k = 0; k < 5; ++k) ys = f4add(ys, ld4(&xs[0][row0 + k][4 * q0]));
      r0 = r1; r1 = r2; r2 = r3; r3 = r4; r4 = ys;
      if (r >= 2) {
        float4 bs = f4add(f4add(f4add(r0, r1), f4add(r2, r3)), r4);
        size_t g = base + (size_t)(zp0 - 2) * PLANE +
                   (size_t)(y0 + row0) * LEN + (x0 + 4 * q0);
        float4 mk = ld4(mask + g);
        acc += bs.x * bs.x * mk.x + bs.y * bs.y * mk.y +
               bs.z * bs.z * mk.z + bs.w * bs.w * mk.w;
      }
    }
    {
      float4 ys = make_float4(0.f, 0.f, 0.f, 0.f);
#pragma unroll
      for (int k = 0; k < 5; ++k) ys = f4add(ys, ld4(&xs[1][row0 + k][4 * q0]));
      r0 = r1; r1 = r2; r2 = r3; r3 = r4; r4 = ys;
      if (r >= 2) {
        float4 bs = f4add(f4add(f4add(r0, r1), f4add(r2, r3)), r4);
        size_t g = base + (size_t)(zp0 - 1) * PLANE +
                   (size_t)(y0 + row0) * LEN + (x0 + 4 * q0);
        float4 mk = ld4(mask + g);
        acc += bs.x * bs.x * mk.x + bs.y * bs.y * mk.y +
               bs.z * bs.z * mk.z + bs.w * bs.w * mk.w;
      }
    }
    __syncthreads();
  }

#pragma unroll
  for (int o = 32; o > 0; o >>= 1) acc += __shfl_down(acc, o, 64);
  int lane = tid & 63, wid = tid >> 6;
  if (lane == 0) wsum[wid] = acc;
  __syncthreads();
  if (tid == 0) {
    float t = 0.f;
#pragma unroll
    for (int w = 0; w < BLK / 64; ++w) t += wsum[w];
    atomicAdd(out, -t);
  }
}

}  // namespace

extern "C" void kernel_launch(void* const* d_in, const int* in_sizes, int n_in,
                              void* d_out, int out_size, void* d_ws, size_t ws_size,
                              hipStream_t stream) {
  const float* F    = (const float*)d_in[0];
  const float* M    = (const float*)d_in[1];
  const float* mask = (const float*)d_in[2];
  float* out = (float*)d_out;

  const size_t bufB = (size_t)(2 * VOL) * sizeof(float);
  char* ws = (char*)d_ws;
  float* dF = (float*)ws;
  float* dM = (float*)(ws + bufB);
  float* pB = (float*)(ws + 2 * bufB);

  hipMemsetAsync(d_out, 0, sizeof(float), stream);

  dim3 grd(LEN / TX, LEN / TY, NCHZ * 2), blk(BLK);

  slab2<0><<<grd, blk, 0, stream>>>(F, M, dF, dM);
  slab2<1><<<grd, blk, 0, stream>>>(dF, dM, pB, nullptr);
  slab1_reduce<<<grd, blk, 0, stream>>>(pB, mask, out);
}